// Round 16
// baseline (191.283 us; speedup 1.0000x reference)
//
#include <hip/hip_runtime.h>
#include <hip/hip_bf16.h>

// ---- problem geometry ----
#define NROWS   131072          // 32*4096
#define DIM     64
#define NEMB    512
// output offsets (floats)
#define OUT_Q     0
#define OUT_DIFF  8388608
#define OUT_IND   8388609
#define OUT_OH    8519681      // 8388609 + 131072
#define OUT_ES    8520193      // OUT_OH + 512
// ws layout (floats) -- audited r16 (u32[N] = N float slots)
#define WS_EN     0             // f32[512]                        -> 512
#define WS_ET     512           // f32[512][64] embedT             -> 33280
#define WS_EB     33280         // bf16[65536] = 32768 floats      -> 66048
#define WS_JIDX   66048         // u32[131072]                     -> 197120
#define WS_HIST   197120        // u32[512*16]                     -> 205312
#define WS_CURS   205312        // u32[16*512] transposed [p][j]   -> 213504
#define WS_FBUCK  213504        // u32[131072] flist/bucket        -> 344576
#define WS_ACC    344576        // f32[512][64]                    -> 377344
#define WS_DPART  377344        // f32[4096]                       -> 381440
#define WS_NFLAG  381440        // u32[16]                         -> 381456
#define WS_NEED   381456        // 1.53 MB < proven-available 1.59 MB
#define NWAVE_FIN 4096          // 32 positions/wave: 4 waves/SIMD in finsum2
#define NCOPY     16
#define TIE_TAU   0.05f

typedef float  f32x4  __attribute__((ext_vector_type(4)));
typedef short  s16x8  __attribute__((ext_vector_type(8)));

__device__ __forceinline__ unsigned short f2bf(float f) {
  unsigned u = __float_as_uint(f);
  return (unsigned short)((u + 0x7FFFu + ((u >> 16) & 1u)) >> 16);
}
__device__ __forceinline__ float bf2f(unsigned short h) {
  return __uint_as_float(((unsigned)h) << 16);
}

__global__ __launch_bounds__(256) void vq_prep(const float* __restrict__ embed,
                                               float* __restrict__ ws,
                                               float* __restrict__ out, int mode) {
  const int tid = blockIdx.x * 256 + threadIdx.x;
  const int nth = gridDim.x * 256;
  for (int e = tid; e < NEMB * DIM; e += nth) {          // embedT[j][d]
    int j = e >> 6, d = e & 63;
    ws[WS_ET + e] = embed[d * NEMB + j];
  }
  for (int j = tid; j < NEMB; j += nth) {                // en[j], np-order fmaf chain
    float s = 0.f;
    for (int d = 0; d < DIM; ++d) {
      float v = embed[d * NEMB + j];
      s = fmaf(v, v, s);
    }
    ws[WS_EN + j] = s;
  }
  if (mode == 2) {
    // EB entry f = (((T*4+c)*4+g)*16+nl)*8+i ; code j=T*16+nl ; d=(c&1)*32+g*8+i
    // byte offset = T*4096 + c*1024 + g*256 + nl*16 + 2*i
    // c0 = eh win0, c1 = eh win1, c2 = el win0, c3 = el win1
    unsigned short* eb = reinterpret_cast<unsigned short*>(ws + WS_EB);
    for (int f = tid; f < NEMB * 128; f += nth) {
      int i  = f & 7;
      int nl = (f >> 3) & 15;
      int g  = (f >> 7) & 3;
      int c  = (f >> 9) & 3;
      int T  = f >> 11;
      int j  = T * 16 + nl;
      int d  = (c & 1) * 32 + g * 8 + i;
      float e = embed[d * NEMB + j];
      unsigned short eh = f2bf(e);
      unsigned short v  = (c < 2) ? eh : f2bf(e - bf2f(eh));
      eb[f] = v;
    }
    unsigned* hist = reinterpret_cast<unsigned*>(ws + WS_HIST);
    for (int k = tid; k < NEMB * NCOPY; k += nth) hist[k] = 0u;
    for (int e = tid; e < NEMB * DIM; e += nth) ws[WS_ACC + e] = 0.f;
    if (tid == 0) reinterpret_cast<unsigned*>(ws + WS_NFLAG)[0] = 0u;
  } else {
    if (tid == 0) out[OUT_DIFF] = 0.f;
    for (int e = tid; e < NEMB + NEMB * DIM; e += nth) out[OUT_OH + e] = 0.f;
  }
}

#define MFMA16(A, B, C) __builtin_amdgcn_mfma_f32_16x16x32_bf16((A), (B), (C), 0, 0, 0)

// 3-term bf16-split MFMA distance kernel + top-2 tie flagging + fused
// per-(code,copy) histogram (replaces the standalone vq_hist kernel).
__global__ __launch_bounds__(256) void vq_distm(
    const float* __restrict__ input, const float* __restrict__ ws,
    unsigned* __restrict__ jidx, unsigned* __restrict__ nflag,
    unsigned* __restrict__ flist, unsigned* __restrict__ hist) {
  __shared__ float en_lds[NEMB];
  const int tid  = threadIdx.x;
  const int lane = tid & 63;
  const int wid  = tid >> 6;
  const int nl   = lane & 15;        // M/N index within tile
  const int g    = lane >> 4;        // K-group
  en_lds[tid]       = ws[WS_EN + tid];
  en_lds[tid + 256] = ws[WS_EN + tid + 256];

  const int rowBase = blockIdx.x * 128 + wid * 32;

  s16x8 ah0_0, al0_0, ah1_0, al1_0;   // tile0: window0(hi/lo), window1(hi/lo)
  s16x8 ah0_1, al0_1, ah1_1, al1_1;   // tile1
#define CVT1(V, H, L, O) { float _v = (V); unsigned _u = __float_as_uint(_v); \
    unsigned _r = (_u + 0x7FFFu + ((_u >> 16) & 1u)) >> 16; \
    float _hf = __uint_as_float(_r << 16); float _lf = _v - _hf; \
    unsigned _ul = __float_as_uint(_lf); \
    H[O] = (short)(unsigned short)_r; \
    L[O] = (short)(unsigned short)((_ul + 0x7FFFu + ((_ul >> 16) & 1u)) >> 16); }
#define CVT4(V, H, L, O) CVT1((V).x, H, L, (O)+0) CVT1((V).y, H, L, (O)+1) \
                         CVT1((V).z, H, L, (O)+2) CVT1((V).w, H, L, (O)+3)
  {
    const float* p0 = input + (size_t)(rowBase + nl) * DIM + g * 8;
    float4 a0 = *reinterpret_cast<const float4*>(p0);
    float4 a1 = *reinterpret_cast<const float4*>(p0 + 4);
    float4 b0 = *reinterpret_cast<const float4*>(p0 + 32);
    float4 b1 = *reinterpret_cast<const float4*>(p0 + 36);
    CVT4(a0, ah0_0, al0_0, 0) CVT4(a1, ah0_0, al0_0, 4)
    CVT4(b0, ah1_0, al1_0, 0) CVT4(b1, ah1_0, al1_0, 4)
    const float* p1 = input + (size_t)(rowBase + 16 + nl) * DIM + g * 8;
    float4 c0 = *reinterpret_cast<const float4*>(p1);
    float4 c1 = *reinterpret_cast<const float4*>(p1 + 4);
    float4 d0 = *reinterpret_cast<const float4*>(p1 + 32);
    float4 d1 = *reinterpret_cast<const float4*>(p1 + 36);
    CVT4(c0, ah0_1, al0_1, 0) CVT4(c1, ah0_1, al0_1, 4)
    CVT4(d0, ah1_1, al1_1, 0) CVT4(d1, ah1_1, al1_1, 4)
  }
  __syncthreads();   // en_lds visibility

  float bD0[4], bD1[4], b2D0[4], b2D1[4]; int bJ0[4], bJ1[4];
#pragma unroll
  for (int r = 0; r < 4; ++r) {
    bD0[r] = 3.4e38f; bD1[r] = 3.4e38f; b2D0[r] = 3.4e38f; b2D1[r] = 3.4e38f;
    bJ0[r] = 0; bJ1[r] = 0;
  }

  const char* ebp = reinterpret_cast<const char*>(ws + WS_EB) + (size_t)lane * 16;
#pragma unroll 1
  for (int T = 0; T < 32; ++T) {
    const char* bt = ebp + (size_t)T * 4096;
    s16x8 B0 = *reinterpret_cast<const s16x8*>(bt);          // eh win0
    s16x8 B1 = *reinterpret_cast<const s16x8*>(bt + 1024);   // eh win1
    s16x8 B2 = *reinterpret_cast<const s16x8*>(bt + 2048);   // el win0
    s16x8 B3 = *reinterpret_cast<const s16x8*>(bt + 3072);   // el win1
    f32x4 aE0 = {0.f, 0.f, 0.f, 0.f}, aO0 = {0.f, 0.f, 0.f, 0.f};
    f32x4 aE1 = {0.f, 0.f, 0.f, 0.f}, aO1 = {0.f, 0.f, 0.f, 0.f};
    aE0 = MFMA16(ah0_0, B0, aE0); aE1 = MFMA16(ah0_1, B0, aE1);
    aO0 = MFMA16(ah1_0, B1, aO0); aO1 = MFMA16(ah1_1, B1, aO1);
    aE0 = MFMA16(al0_0, B0, aE0); aE1 = MFMA16(al0_1, B0, aE1);
    aO0 = MFMA16(al1_0, B1, aO0); aO1 = MFMA16(al1_1, B1, aO1);
    aE0 = MFMA16(ah0_0, B2, aE0); aE1 = MFMA16(ah0_1, B2, aE1);
    aO0 = MFMA16(ah1_0, B3, aO0); aO1 = MFMA16(ah1_1, B3, aO1);

    const float en0 = en_lds[(T << 4) | nl];
    const int jj = (T << 4) | nl;
#pragma unroll
    for (int r = 0; r < 4; ++r) {
      float d0 = fmaf(-2.0f, aE0[r] + aO0[r], en0);   // xx dropped: constant/row
      float d1 = fmaf(-2.0f, aE1[r] + aO1[r], en0);
      if (d0 < bD0[r]) { b2D0[r] = bD0[r]; bD0[r] = d0; bJ0[r] = jj; }
      else if (d0 < b2D0[r]) { b2D0[r] = d0; }
      if (d1 < bD1[r]) { b2D1[r] = bD1[r]; bD1[r] = d1; bJ1[r] = jj; }
      else if (d1 < b2D1[r]) { b2D1[r] = d1; }
    }
  }

  // per-row lex argmin over 16 lanes + global second-best; flag near-ties;
  // fused histogram write (r16): one atomic per row into hist[(J<<4)+p].
#pragma unroll
  for (int r = 0; r < 4; ++r) {
#pragma unroll
    for (int t = 0; t < 2; ++t) {
      float D   = t ? bD1[r]  : bD0[r];
      float D2l = t ? b2D1[r] : b2D0[r];
      int   J   = t ? bJ1[r]  : bJ0[r];
      float Dm = D; int Jm = J;
#pragma unroll
      for (int s = 1; s <= 8; s <<= 1) {
        float oD = __shfl_xor(Dm, s, 64);
        int   oJ = __shfl_xor(Jm, s, 64);
        if (oD < Dm || (oD == Dm && oJ < Jm)) { Dm = oD; Jm = oJ; }
      }
      float cand = (D == Dm && J == Jm) ? D2l : D;
#pragma unroll
      for (int s = 1; s <= 8; s <<= 1) {
        float oc = __shfl_xor(cand, s, 64);
        if (oc < cand) cand = oc;
      }
      if (nl == 0) {
        int row = rowBase + t * 16 + g * 4 + r;
        jidx[row] = (unsigned)Jm;
        atomicAdd(hist + (((unsigned)Jm) << 4) + ((unsigned)(row >> 8) & (NCOPY - 1)), 1u);
        if (cand - Dm < TIE_TAU) {
          unsigned pos = atomicAdd(nflag, 1u);
          flist[pos] = (unsigned)row;
        }
      }
    }
  }
}

// Block-per-row exact fp32 re-argmin (r12 proven) + histogram fixup for the
// ~0.5% of rows whose index changes (keeps the fused distm histogram exact).
__global__ __launch_bounds__(256) void vq_refine(
    const float* __restrict__ input, const float* __restrict__ embed,
    const float* __restrict__ ws, const unsigned* __restrict__ nflag,
    const unsigned* __restrict__ flist, unsigned* __restrict__ jidx,
    unsigned* __restrict__ hist) {
  __shared__ float xl[DIM];
  __shared__ float rD[256];
  __shared__ int   rJ[256];
  const int tid = threadIdx.x;
  const unsigned n = nflag[0];

  for (unsigned t = blockIdx.x; t < n; t += gridDim.x) {
    const unsigned row = flist[t];
    if (tid < DIM) xl[tid] = input[(size_t)row * DIM + tid];
    __syncthreads();

    float xx = 0.f;
#pragma unroll
    for (int d = 0; d < DIM; ++d) xx = fmaf(xl[d], xl[d], xx);

    float best = 3.4e38f; int bj = tid;
#pragma unroll
    for (int h = 0; h < 2; ++h) {
      const int j = (h << 8) + tid;
      float acc = 0.f;
#pragma unroll
      for (int d = 0; d < DIM; ++d)
        acc = fmaf(xl[d], embed[d * NEMB + j], acc);
      float dist = (xx - 2.0f * acc) + ws[WS_EN + j];  // np expr order
      if (dist < best) { best = dist; bj = j; }
    }
    rD[tid] = best; rJ[tid] = bj;
    __syncthreads();
#pragma unroll
    for (int s = 128; s > 0; s >>= 1) {
      if (tid < s) {
        float oD = rD[tid + s]; int oJ = rJ[tid + s];
        if (oD < rD[tid] || (oD == rD[tid] && oJ < rJ[tid])) {
          rD[tid] = oD; rJ[tid] = oJ;
        }
      }
      __syncthreads();
    }
    if (tid == 0) {
      const unsigned newJ = (unsigned)rJ[0];
      const unsigned oldJ = jidx[row];
      if (newJ != oldJ) {
        const unsigned p = (row >> 8) & (NCOPY - 1);
        atomicSub(hist + (oldJ << 4) + p, 1u);
        atomicAdd(hist + (newJ << 4) + p, 1u);
        jidx[row] = newJ;
      }
    }
    __syncthreads();
  }
}

// Scan: thread j sums its 16 per-copy counts, block-scans totals, then lays
// out per-copy cursor bases in TRANSPOSED layout curs[p][j] (r15 proven:
// copies in distinct cache lines -> no line-level atomic serialization).
__global__ __launch_bounds__(512) void vq_scan(
    const unsigned* __restrict__ hist, unsigned* __restrict__ curs,
    float* __restrict__ out) {
  __shared__ unsigned lsum[8];
  const int tid = threadIdx.x, lane = tid & 63, wid = tid >> 6;
  unsigned h[NCOPY];
  unsigned tot = 0;
#pragma unroll
  for (int p = 0; p < NCOPY; ++p) { h[p] = hist[(tid << 4) + p]; tot += h[p]; }
  unsigned v = tot;
#pragma unroll
  for (int s = 1; s < 64; s <<= 1) {
    unsigned t = (unsigned)__shfl_up((int)v, s, 64);
    if (lane >= s) v += t;
  }
  if (lane == 63) lsum[wid] = v;
  __syncthreads();
  if (tid == 0) {
    unsigned run = 0;
#pragma unroll
    for (int w = 0; w < 8; ++w) { unsigned t = lsum[w]; lsum[w] = run; run += t; }
  }
  __syncthreads();
  unsigned run = v - tot + lsum[wid];     // exclusive prefix for code j
#pragma unroll
  for (int p = 0; p < NCOPY; ++p) { curs[p * NEMB + tid] = run; run += h[p]; }
  out[OUT_OH + tid] = (float)tot;
}

__global__ __launch_bounds__(256) void vq_scatter(
    const unsigned* __restrict__ jidx, unsigned* __restrict__ curs,
    unsigned* __restrict__ bucket) {
  const int i = blockIdx.x * 256 + threadIdx.x;
  const unsigned J = jidx[i];
  const unsigned pos =
      atomicAdd(curs + (unsigned)(blockIdx.x & (NCOPY - 1)) * NEMB + J, 1u);
  bucket[pos] = (unsigned)i;
}

// Position-balanced segmented sum; r16: 32 positions/wave (4096 waves ->
// 4 waves/SIMD, double the latency-hiding of r15's 2048).
__global__ __launch_bounds__(256) void vq_finsum2(
    const float* __restrict__ input, const float* __restrict__ ws,
    const unsigned* __restrict__ jidx, const unsigned* __restrict__ bucket,
    float* __restrict__ ws_acc, float* __restrict__ dpart,
    float* __restrict__ out) {
  const int tid  = threadIdx.x;
  const int lane = tid & 63;
  const int wid  = tid >> 6;
  const int waveIdx = blockIdx.x * 4 + wid;
  const unsigned posBase = (unsigned)waveIdx * 32;

  float sum = 0.f, dacc = 0.f, q = 0.f;
  int jcur = -1;
  unsigned row = bucket[posBase];
  int j = (int)jidx[row];
#pragma unroll 1
  for (int p = 0; p < 32; ++p) {
    unsigned rowN = 0; int jN = 0;
    if (p < 31) {
      rowN = bucket[posBase + p + 1];
      jN = (int)jidx[rowN];
    }
    if (j != jcur) {
      if (jcur >= 0) atomicAdd(ws_acc + (size_t)jcur * DIM + lane, sum);
      sum = 0.f; jcur = j;
      q = ws[WS_ET + (size_t)j * DIM + lane];
    }
    const float xv = input[(size_t)row * DIM + lane];
    sum += xv;
    const float er = q - xv;
    dacc = fmaf(er, er, dacc);
    out[OUT_Q + (size_t)row * DIM + lane] = q;
    if (lane == 0) out[OUT_IND + row] = (float)j;
    row = rowN; j = jN;
  }
  atomicAdd(ws_acc + (size_t)jcur * DIM + lane, sum);
#pragma unroll
  for (int s = 1; s < 64; s <<= 1) dacc += __shfl_xor(dacc, s, 64);
  if (lane == 0) dpart[waveIdx] = dacc;
}

__global__ __launch_bounds__(256) void vq_es(
    const float* __restrict__ ws_acc, const float* __restrict__ dpart,
    float* __restrict__ out, int ndpart) {
  const int e = blockIdx.x * 256 + threadIdx.x;
  const int d = e >> 9, j = e & 511;
  out[OUT_ES + e] = ws_acc[(size_t)j * DIM + d];
  if (blockIdx.x == 0) {
    __shared__ float red[256];
    const int tid = threadIdx.x;
    float sum = 0.f;
    for (int k = tid; k < ndpart; k += 256) sum += dpart[k];
    red[tid] = sum;
    __syncthreads();
#pragma unroll
    for (int t = 128; t > 0; t >>= 1) {
      if (tid < t) red[tid] += red[tid + t];
      __syncthreads();
    }
    if (tid == 0) out[OUT_DIFF] = red[0] * (1.0f / (float)(NROWS * DIM));
  }
}

// Fallback for tiny ws: direct atomics (round-2 proven).
__global__ __launch_bounds__(256) void vq_mono(
    const float* __restrict__ input, const float* __restrict__ embed,
    const float* __restrict__ ws, float* __restrict__ out) {
  const int i = blockIdx.x * 256 + threadIdx.x;
  float x[DIM];
  const float4* xin = reinterpret_cast<const float4*>(input + (size_t)i * DIM);
#pragma unroll
  for (int k = 0; k < 16; ++k) {
    float4 v = xin[k];
    x[4 * k + 0] = v.x; x[4 * k + 1] = v.y; x[4 * k + 2] = v.z; x[4 * k + 3] = v.w;
  }
  float xx = 0.f;
#pragma unroll
  for (int d = 0; d < DIM; ++d) xx = fmaf(x[d], x[d], xx);
  float best = 3.4e38f; int bj = 0;
#pragma unroll 1
  for (int jt = 0; jt < NEMB; jt += 8) {
    float acc[8];
#pragma unroll
    for (int u = 0; u < 8; ++u) acc[u] = 0.f;
#pragma unroll
    for (int d = 0; d < DIM; ++d) {
      const float xv = x[d];
#pragma unroll
      for (int u = 0; u < 8; ++u)
        acc[u] = fmaf(xv, embed[d * NEMB + jt + u], acc[u]);
    }
#pragma unroll
    for (int u = 0; u < 8; ++u) {
      float dist = (xx - 2.0f * acc[u]) + ws[WS_EN + jt + u];
      if (dist < best) { best = dist; bj = jt + u; }
    }
  }
  out[OUT_IND + i] = (float)bj;
  const float4* qr = reinterpret_cast<const float4*>(ws + WS_ET + (size_t)bj * DIM);
  float4* qo = reinterpret_cast<float4*>(out + (size_t)i * DIM);
  float dsum = 0.f;
#pragma unroll
  for (int k = 0; k < 16; ++k) {
    float4 q = qr[k];
    float e0 = q.x - x[4 * k + 0]; dsum = fmaf(e0, e0, dsum);
    float e1 = q.y - x[4 * k + 1]; dsum = fmaf(e1, e1, dsum);
    float e2 = q.z - x[4 * k + 2]; dsum = fmaf(e2, e2, dsum);
    float e3 = q.w - x[4 * k + 3]; dsum = fmaf(e3, e3, dsum);
    qo[k] = q;
  }
  __shared__ float red[256];
  red[threadIdx.x] = dsum;
  __syncthreads();
#pragma unroll
  for (int s = 128; s > 0; s >>= 1) {
    if (threadIdx.x < s) red[threadIdx.x] += red[threadIdx.x + s];
    __syncthreads();
  }
  if (threadIdx.x == 0)
    atomicAdd(out + OUT_DIFF, red[0] * (1.0f / (float)(NROWS * DIM)));
  atomicAdd(out + OUT_OH + bj, 1.0f);
#pragma unroll
  for (int d = 0; d < DIM; ++d) atomicAdd(out + OUT_ES + d * NEMB + bj, x[d]);
}

extern "C" void kernel_launch(void* const* d_in, const int* in_sizes, int n_in,
                              void* d_out, int out_size, void* d_ws, size_t ws_size,
                              hipStream_t stream) {
  const float* input = (const float*)d_in[0];
  const float* embed = (const float*)d_in[1];
  float* out = (float*)d_out;
  float* ws  = (float*)d_ws;

  long ws_floats = (long)(ws_size / 4);

  if (ws_floats >= WS_NEED) {
    unsigned* jidx   = reinterpret_cast<unsigned*>(ws + WS_JIDX);
    unsigned* hist   = reinterpret_cast<unsigned*>(ws + WS_HIST);
    unsigned* curs   = reinterpret_cast<unsigned*>(ws + WS_CURS);
    unsigned* fbuck  = reinterpret_cast<unsigned*>(ws + WS_FBUCK); // flist then bucket
    float*    ws_acc = ws + WS_ACC;
    float*    dpart  = ws + WS_DPART;
    unsigned* nflag  = reinterpret_cast<unsigned*>(ws + WS_NFLAG);
    vq_prep<<<256, 256, 0, stream>>>(embed, ws, out, 2);
    vq_distm<<<NROWS / 128, 256, 0, stream>>>(input, ws, jidx, nflag, fbuck, hist);
    vq_refine<<<512, 256, 0, stream>>>(input, embed, ws, nflag, fbuck, jidx, hist);
    vq_scan<<<1, 512, 0, stream>>>(hist, curs, out);
    vq_scatter<<<NROWS / 256, 256, 0, stream>>>(jidx, curs, fbuck);
    vq_finsum2<<<NWAVE_FIN / 4, 256, 0, stream>>>(input, ws, jidx, fbuck,
                                                  ws_acc, dpart, out);
    vq_es<<<NEMB * DIM / 256, 256, 0, stream>>>(ws_acc, dpart, out, NWAVE_FIN);
  } else {
    vq_prep<<<256, 256, 0, stream>>>(embed, ws, out, 0);
    vq_mono<<<NROWS / 256, 256, 0, stream>>>(input, embed, ws, out);
  }
}

// Round 17
// 135.338 us; speedup vs baseline: 1.4134x; 1.4134x over previous
//
#include <hip/hip_runtime.h>
#include <hip/hip_bf16.h>

// ---- problem geometry ----
#define NROWS   131072          // 32*4096
#define DIM     64
#define NEMB    512
// output offsets (floats)
#define OUT_Q     0
#define OUT_DIFF  8388608
#define OUT_IND   8388609
#define OUT_OH    8519681      // 8388609 + 131072
#define OUT_ES    8520193      // OUT_OH + 512
// ws layout (floats) -- audited r17 (u32[N] = N float slots)
#define WS_EN     0             // f32[512]                        -> 512
#define WS_ET     512           // f32[512][64] embedT             -> 33280
#define WS_EB     33280         // bf16[65536] = 32768 floats      -> 66048
#define WS_JIDX   66048         // u32[131072]                     -> 197120
#define WS_HIST   197120        // u32[512*16]                     -> 205312
#define WS_CURS   205312        // u32[16*512] transposed [p][j]   -> 213504
#define WS_FBUCK  213504        // u32[131072] flist/bucket        -> 344576
#define WS_ACC    344576        // f32[512][64]                    -> 377344
#define WS_DPART  377344        // f32[4096]                       -> 381440
#define WS_NFLAG  381440        // u32[16]                         -> 381456
#define WS_NEED   381456        // 1.53 MB < proven-available 1.59 MB
#define NWAVE_FIN 4096          // 32 positions/wave: 4 waves/SIMD in finsum2
#define NCOPY     16
#define TIE_TAU   0.05f

typedef float  f32x4  __attribute__((ext_vector_type(4)));
typedef short  s16x8  __attribute__((ext_vector_type(8)));

__device__ __forceinline__ unsigned short f2bf(float f) {
  unsigned u = __float_as_uint(f);
  return (unsigned short)((u + 0x7FFFu + ((u >> 16) & 1u)) >> 16);
}
__device__ __forceinline__ float bf2f(unsigned short h) {
  return __uint_as_float(((unsigned)h) << 16);
}

__global__ __launch_bounds__(256) void vq_prep(const float* __restrict__ embed,
                                               float* __restrict__ ws,
                                               float* __restrict__ out, int mode) {
  const int tid = blockIdx.x * 256 + threadIdx.x;
  const int nth = gridDim.x * 256;
  for (int e = tid; e < NEMB * DIM; e += nth) {          // embedT[j][d]
    int j = e >> 6, d = e & 63;
    ws[WS_ET + e] = embed[d * NEMB + j];
  }
  for (int j = tid; j < NEMB; j += nth) {                // en[j], np-order fmaf chain
    float s = 0.f;
    for (int d = 0; d < DIM; ++d) {
      float v = embed[d * NEMB + j];
      s = fmaf(v, v, s);
    }
    ws[WS_EN + j] = s;
  }
  if (mode == 2) {
    // EB entry f = (((T*4+c)*4+g)*16+nl)*8+i ; code j=T*16+nl ; d=(c&1)*32+g*8+i
    // byte offset = T*4096 + c*1024 + g*256 + nl*16 + 2*i
    // c0 = eh win0, c1 = eh win1, c2 = el win0, c3 = el win1
    unsigned short* eb = reinterpret_cast<unsigned short*>(ws + WS_EB);
    for (int f = tid; f < NEMB * 128; f += nth) {
      int i  = f & 7;
      int nl = (f >> 3) & 15;
      int g  = (f >> 7) & 3;
      int c  = (f >> 9) & 3;
      int T  = f >> 11;
      int j  = T * 16 + nl;
      int d  = (c & 1) * 32 + g * 8 + i;
      float e = embed[d * NEMB + j];
      unsigned short eh = f2bf(e);
      unsigned short v  = (c < 2) ? eh : f2bf(e - bf2f(eh));
      eb[f] = v;
    }
    unsigned* hist = reinterpret_cast<unsigned*>(ws + WS_HIST);
    for (int k = tid; k < NEMB * NCOPY; k += nth) hist[k] = 0u;
    for (int e = tid; e < NEMB * DIM; e += nth) ws[WS_ACC + e] = 0.f;
    if (tid == 0) reinterpret_cast<unsigned*>(ws + WS_NFLAG)[0] = 0u;
  } else {
    if (tid == 0) out[OUT_DIFF] = 0.f;
    for (int e = tid; e < NEMB + NEMB * DIM; e += nth) out[OUT_OH + e] = 0.f;
  }
}

#define MFMA16(A, B, C) __builtin_amdgcn_mfma_f32_16x16x32_bf16((A), (B), (C), 0, 0, 0)

// 3-term bf16-split MFMA distance kernel + top-2 tie flagging. (r15 proven;
// r16's fused hist atomic reverted: hist[(J<<4)+p] put all copies of a code
// in ONE cache line -> 256-deep line-serialized atomics inside distm.)
__global__ __launch_bounds__(256) void vq_distm(
    const float* __restrict__ input, const float* __restrict__ ws,
    unsigned* __restrict__ jidx, unsigned* __restrict__ nflag,
    unsigned* __restrict__ flist) {
  __shared__ float en_lds[NEMB];
  const int tid  = threadIdx.x;
  const int lane = tid & 63;
  const int wid  = tid >> 6;
  const int nl   = lane & 15;        // M/N index within tile
  const int g    = lane >> 4;        // K-group
  en_lds[tid]       = ws[WS_EN + tid];
  en_lds[tid + 256] = ws[WS_EN + tid + 256];

  const int rowBase = blockIdx.x * 128 + wid * 32;

  s16x8 ah0_0, al0_0, ah1_0, al1_0;   // tile0: window0(hi/lo), window1(hi/lo)
  s16x8 ah0_1, al0_1, ah1_1, al1_1;   // tile1
#define CVT1(V, H, L, O) { float _v = (V); unsigned _u = __float_as_uint(_v); \
    unsigned _r = (_u + 0x7FFFu + ((_u >> 16) & 1u)) >> 16; \
    float _hf = __uint_as_float(_r << 16); float _lf = _v - _hf; \
    unsigned _ul = __float_as_uint(_lf); \
    H[O] = (short)(unsigned short)_r; \
    L[O] = (short)(unsigned short)((_ul + 0x7FFFu + ((_ul >> 16) & 1u)) >> 16); }
#define CVT4(V, H, L, O) CVT1((V).x, H, L, (O)+0) CVT1((V).y, H, L, (O)+1) \
                         CVT1((V).z, H, L, (O)+2) CVT1((V).w, H, L, (O)+3)
  {
    const float* p0 = input + (size_t)(rowBase + nl) * DIM + g * 8;
    float4 a0 = *reinterpret_cast<const float4*>(p0);
    float4 a1 = *reinterpret_cast<const float4*>(p0 + 4);
    float4 b0 = *reinterpret_cast<const float4*>(p0 + 32);
    float4 b1 = *reinterpret_cast<const float4*>(p0 + 36);
    CVT4(a0, ah0_0, al0_0, 0) CVT4(a1, ah0_0, al0_0, 4)
    CVT4(b0, ah1_0, al1_0, 0) CVT4(b1, ah1_0, al1_0, 4)
    const float* p1 = input + (size_t)(rowBase + 16 + nl) * DIM + g * 8;
    float4 c0 = *reinterpret_cast<const float4*>(p1);
    float4 c1 = *reinterpret_cast<const float4*>(p1 + 4);
    float4 d0 = *reinterpret_cast<const float4*>(p1 + 32);
    float4 d1 = *reinterpret_cast<const float4*>(p1 + 36);
    CVT4(c0, ah0_1, al0_1, 0) CVT4(c1, ah0_1, al0_1, 4)
    CVT4(d0, ah1_1, al1_1, 0) CVT4(d1, ah1_1, al1_1, 4)
  }
  __syncthreads();   // en_lds visibility

  float bD0[4], bD1[4], b2D0[4], b2D1[4]; int bJ0[4], bJ1[4];
#pragma unroll
  for (int r = 0; r < 4; ++r) {
    bD0[r] = 3.4e38f; bD1[r] = 3.4e38f; b2D0[r] = 3.4e38f; b2D1[r] = 3.4e38f;
    bJ0[r] = 0; bJ1[r] = 0;
  }

  const char* ebp = reinterpret_cast<const char*>(ws + WS_EB) + (size_t)lane * 16;
#pragma unroll 1
  for (int T = 0; T < 32; ++T) {
    const char* bt = ebp + (size_t)T * 4096;
    s16x8 B0 = *reinterpret_cast<const s16x8*>(bt);          // eh win0
    s16x8 B1 = *reinterpret_cast<const s16x8*>(bt + 1024);   // eh win1
    s16x8 B2 = *reinterpret_cast<const s16x8*>(bt + 2048);   // el win0
    s16x8 B3 = *reinterpret_cast<const s16x8*>(bt + 3072);   // el win1
    f32x4 aE0 = {0.f, 0.f, 0.f, 0.f}, aO0 = {0.f, 0.f, 0.f, 0.f};
    f32x4 aE1 = {0.f, 0.f, 0.f, 0.f}, aO1 = {0.f, 0.f, 0.f, 0.f};
    aE0 = MFMA16(ah0_0, B0, aE0); aE1 = MFMA16(ah0_1, B0, aE1);
    aO0 = MFMA16(ah1_0, B1, aO0); aO1 = MFMA16(ah1_1, B1, aO1);
    aE0 = MFMA16(al0_0, B0, aE0); aE1 = MFMA16(al0_1, B0, aE1);
    aO0 = MFMA16(al1_0, B1, aO0); aO1 = MFMA16(al1_1, B1, aO1);
    aE0 = MFMA16(ah0_0, B2, aE0); aE1 = MFMA16(ah0_1, B2, aE1);
    aO0 = MFMA16(ah1_0, B3, aO0); aO1 = MFMA16(ah1_1, B3, aO1);

    const float en0 = en_lds[(T << 4) | nl];
    const int jj = (T << 4) | nl;
#pragma unroll
    for (int r = 0; r < 4; ++r) {
      float d0 = fmaf(-2.0f, aE0[r] + aO0[r], en0);   // xx dropped: constant/row
      float d1 = fmaf(-2.0f, aE1[r] + aO1[r], en0);
      if (d0 < bD0[r]) { b2D0[r] = bD0[r]; bD0[r] = d0; bJ0[r] = jj; }
      else if (d0 < b2D0[r]) { b2D0[r] = d0; }
      if (d1 < bD1[r]) { b2D1[r] = bD1[r]; bD1[r] = d1; bJ1[r] = jj; }
      else if (d1 < b2D1[r]) { b2D1[r] = d1; }
    }
  }

  // per-row lex argmin over 16 lanes + global second-best; flag near-ties
#pragma unroll
  for (int r = 0; r < 4; ++r) {
#pragma unroll
    for (int t = 0; t < 2; ++t) {
      float D   = t ? bD1[r]  : bD0[r];
      float D2l = t ? b2D1[r] : b2D0[r];
      int   J   = t ? bJ1[r]  : bJ0[r];
      float Dm = D; int Jm = J;
#pragma unroll
      for (int s = 1; s <= 8; s <<= 1) {
        float oD = __shfl_xor(Dm, s, 64);
        int   oJ = __shfl_xor(Jm, s, 64);
        if (oD < Dm || (oD == Dm && oJ < Jm)) { Dm = oD; Jm = oJ; }
      }
      float cand = (D == Dm && J == Jm) ? D2l : D;
#pragma unroll
      for (int s = 1; s <= 8; s <<= 1) {
        float oc = __shfl_xor(cand, s, 64);
        if (oc < cand) cand = oc;
      }
      if (nl == 0) {
        int row = rowBase + t * 16 + g * 4 + r;
        jidx[row] = (unsigned)Jm;
        if (cand - Dm < TIE_TAU) {
          unsigned pos = atomicAdd(nflag, 1u);
          flist[pos] = (unsigned)row;
        }
      }
    }
  }
}

// Block-per-row exact fp32 re-argmin (r12 proven). x in LDS, no scratch.
__global__ __launch_bounds__(256) void vq_refine(
    const float* __restrict__ input, const float* __restrict__ embed,
    const float* __restrict__ ws, const unsigned* __restrict__ nflag,
    const unsigned* __restrict__ flist, unsigned* __restrict__ jidx) {
  __shared__ float xl[DIM];
  __shared__ float rD[256];
  __shared__ int   rJ[256];
  const int tid = threadIdx.x;
  const unsigned n = nflag[0];

  for (unsigned t = blockIdx.x; t < n; t += gridDim.x) {
    const unsigned row = flist[t];
    if (tid < DIM) xl[tid] = input[(size_t)row * DIM + tid];
    __syncthreads();

    float xx = 0.f;
#pragma unroll
    for (int d = 0; d < DIM; ++d) xx = fmaf(xl[d], xl[d], xx);

    float best = 3.4e38f; int bj = tid;
#pragma unroll
    for (int h = 0; h < 2; ++h) {
      const int j = (h << 8) + tid;
      float acc = 0.f;
#pragma unroll
      for (int d = 0; d < DIM; ++d)
        acc = fmaf(xl[d], embed[d * NEMB + j], acc);
      float dist = (xx - 2.0f * acc) + ws[WS_EN + j];  // np expr order
      if (dist < best) { best = dist; bj = j; }
    }
    rD[tid] = best; rJ[tid] = bj;
    __syncthreads();
#pragma unroll
    for (int s = 128; s > 0; s >>= 1) {
      if (tid < s) {
        float oD = rD[tid + s]; int oJ = rJ[tid + s];
        if (oD < rD[tid] || (oD == rD[tid] && oJ < rJ[tid])) {
          rD[tid] = oD; rJ[tid] = oJ;
        }
      }
      __syncthreads();
    }
    if (tid == 0) jidx[row] = (unsigned)rJ[0];
    __syncthreads();
  }
}

// Histogram per (code, copy), LDS-aggregated (r15 proven fast — flush
// atomics are wave-batched, few per line).
__global__ __launch_bounds__(256) void vq_hist(
    const unsigned* __restrict__ jidx, unsigned* __restrict__ hist) {
  __shared__ unsigned lh[NEMB * NCOPY];
  const int tid = threadIdx.x;
  for (int k = tid; k < NEMB * NCOPY; k += 256) lh[k] = 0u;
  __syncthreads();
  for (int i = blockIdx.x * 256 + tid; i < NROWS; i += gridDim.x * 256)
    atomicAdd(&lh[(jidx[i] << 4) + ((i >> 8) & (NCOPY - 1))], 1u);
  __syncthreads();
  for (int k = tid; k < NEMB * NCOPY; k += 256)
    if (lh[k]) atomicAdd(hist + k, lh[k]);
}

// Scan: thread j sums its 16 per-copy counts, block-scans totals, then lays
// out per-copy cursor bases in TRANSPOSED layout curs[p][j] (r15 proven).
__global__ __launch_bounds__(512) void vq_scan(
    const unsigned* __restrict__ hist, unsigned* __restrict__ curs,
    float* __restrict__ out) {
  __shared__ unsigned lsum[8];
  const int tid = threadIdx.x, lane = tid & 63, wid = tid >> 6;
  unsigned h[NCOPY];
  unsigned tot = 0;
#pragma unroll
  for (int p = 0; p < NCOPY; ++p) { h[p] = hist[(tid << 4) + p]; tot += h[p]; }
  unsigned v = tot;
#pragma unroll
  for (int s = 1; s < 64; s <<= 1) {
    unsigned t = (unsigned)__shfl_up((int)v, s, 64);
    if (lane >= s) v += t;
  }
  if (lane == 63) lsum[wid] = v;
  __syncthreads();
  if (tid == 0) {
    unsigned run = 0;
#pragma unroll
    for (int w = 0; w < 8; ++w) { unsigned t = lsum[w]; lsum[w] = run; run += t; }
  }
  __syncthreads();
  unsigned run = v - tot + lsum[wid];     // exclusive prefix for code j
#pragma unroll
  for (int p = 0; p < NCOPY; ++p) { curs[p * NEMB + tid] = run; run += h[p]; }
  out[OUT_OH + tid] = (float)tot;
}

__global__ __launch_bounds__(256) void vq_scatter(
    const unsigned* __restrict__ jidx, unsigned* __restrict__ curs,
    unsigned* __restrict__ bucket) {
  const int i = blockIdx.x * 256 + threadIdx.x;
  const unsigned J = jidx[i];
  const unsigned pos =
      atomicAdd(curs + (unsigned)(blockIdx.x & (NCOPY - 1)) * NEMB + J, 1u);
  bucket[pos] = (unsigned)i;
}

// Position-balanced segmented sum; 32 positions/wave (4096 waves ->
// 4 waves/SIMD, r16's good half).
__global__ __launch_bounds__(256) void vq_finsum2(
    const float* __restrict__ input, const float* __restrict__ ws,
    const unsigned* __restrict__ jidx, const unsigned* __restrict__ bucket,
    float* __restrict__ ws_acc, float* __restrict__ dpart,
    float* __restrict__ out) {
  const int tid  = threadIdx.x;
  const int lane = tid & 63;
  const int wid  = tid >> 6;
  const int waveIdx = blockIdx.x * 4 + wid;
  const unsigned posBase = (unsigned)waveIdx * 32;

  float sum = 0.f, dacc = 0.f, q = 0.f;
  int jcur = -1;
  unsigned row = bucket[posBase];
  int j = (int)jidx[row];
#pragma unroll 1
  for (int p = 0; p < 32; ++p) {
    unsigned rowN = 0; int jN = 0;
    if (p < 31) {
      rowN = bucket[posBase + p + 1];
      jN = (int)jidx[rowN];
    }
    if (j != jcur) {
      if (jcur >= 0) atomicAdd(ws_acc + (size_t)jcur * DIM + lane, sum);
      sum = 0.f; jcur = j;
      q = ws[WS_ET + (size_t)j * DIM + lane];
    }
    const float xv = input[(size_t)row * DIM + lane];
    sum += xv;
    const float er = q - xv;
    dacc = fmaf(er, er, dacc);
    out[OUT_Q + (size_t)row * DIM + lane] = q;
    if (lane == 0) out[OUT_IND + row] = (float)j;
    row = rowN; j = jN;
  }
  atomicAdd(ws_acc + (size_t)jcur * DIM + lane, sum);
#pragma unroll
  for (int s = 1; s < 64; s <<= 1) dacc += __shfl_xor(dacc, s, 64);
  if (lane == 0) dpart[waveIdx] = dacc;
}

__global__ __launch_bounds__(256) void vq_es(
    const float* __restrict__ ws_acc, const float* __restrict__ dpart,
    float* __restrict__ out, int ndpart) {
  const int e = blockIdx.x * 256 + threadIdx.x;
  const int d = e >> 9, j = e & 511;
  out[OUT_ES + e] = ws_acc[(size_t)j * DIM + d];
  if (blockIdx.x == 0) {
    __shared__ float red[256];
    const int tid = threadIdx.x;
    float sum = 0.f;
    for (int k = tid; k < ndpart; k += 256) sum += dpart[k];
    red[tid] = sum;
    __syncthreads();
#pragma unroll
    for (int t = 128; t > 0; t >>= 1) {
      if (tid < t) red[tid] += red[tid + t];
      __syncthreads();
    }
    if (tid == 0) out[OUT_DIFF] = red[0] * (1.0f / (float)(NROWS * DIM));
  }
}

// Fallback for tiny ws: direct atomics (round-2 proven).
__global__ __launch_bounds__(256) void vq_mono(
    const float* __restrict__ input, const float* __restrict__ embed,
    const float* __restrict__ ws, float* __restrict__ out) {
  const int i = blockIdx.x * 256 + threadIdx.x;
  float x[DIM];
  const float4* xin = reinterpret_cast<const float4*>(input + (size_t)i * DIM);
#pragma unroll
  for (int k = 0; k < 16; ++k) {
    float4 v = xin[k];
    x[4 * k + 0] = v.x; x[4 * k + 1] = v.y; x[4 * k + 2] = v.z; x[4 * k + 3] = v.w;
  }
  float xx = 0.f;
#pragma unroll
  for (int d = 0; d < DIM; ++d) xx = fmaf(x[d], x[d], xx);
  float best = 3.4e38f; int bj = 0;
#pragma unroll 1
  for (int jt = 0; jt < NEMB; jt += 8) {
    float acc[8];
#pragma unroll
    for (int u = 0; u < 8; ++u) acc[u] = 0.f;
#pragma unroll
    for (int d = 0; d < DIM; ++d) {
      const float xv = x[d];
#pragma unroll
      for (int u = 0; u < 8; ++u)
        acc[u] = fmaf(xv, embed[d * NEMB + jt + u], acc[u]);
    }
#pragma unroll
    for (int u = 0; u < 8; ++u) {
      float dist = (xx - 2.0f * acc[u]) + ws[WS_EN + jt + u];
      if (dist < best) { best = dist; bj = jt + u; }
    }
  }
  out[OUT_IND + i] = (float)bj;
  const float4* qr = reinterpret_cast<const float4*>(ws + WS_ET + (size_t)bj * DIM);
  float4* qo = reinterpret_cast<float4*>(out + (size_t)i * DIM);
  float dsum = 0.f;
#pragma unroll
  for (int k = 0; k < 16; ++k) {
    float4 q = qr[k];
    float e0 = q.x - x[4 * k + 0]; dsum = fmaf(e0, e0, dsum);
    float e1 = q.y - x[4 * k + 1]; dsum = fmaf(e1, e1, dsum);
    float e2 = q.z - x[4 * k + 2]; dsum = fmaf(e2, e2, dsum);
    float e3 = q.w - x[4 * k + 3]; dsum = fmaf(e3, e3, dsum);
    qo[k] = q;
  }
  __shared__ float red[256];
  red[threadIdx.x] = dsum;
  __syncthreads();
#pragma unroll
  for (int s = 128; s > 0; s >>= 1) {
    if (threadIdx.x < s) red[threadIdx.x] += red[threadIdx.x + s];
    __syncthreads();
  }
  if (threadIdx.x == 0)
    atomicAdd(out + OUT_DIFF, red[0] * (1.0f / (float)(NROWS * DIM)));
  atomicAdd(out + OUT_OH + bj, 1.0f);
#pragma unroll
  for (int d = 0; d < DIM; ++d) atomicAdd(out + OUT_ES + d * NEMB + bj, x[d]);
}

extern "C" void kernel_launch(void* const* d_in, const int* in_sizes, int n_in,
                              void* d_out, int out_size, void* d_ws, size_t ws_size,
                              hipStream_t stream) {
  const float* input = (const float*)d_in[0];
  const float* embed = (const float*)d_in[1];
  float* out = (float*)d_out;
  float* ws  = (float*)d_ws;

  long ws_floats = (long)(ws_size / 4);

  if (ws_floats >= WS_NEED) {
    unsigned* jidx   = reinterpret_cast<unsigned*>(ws + WS_JIDX);
    unsigned* hist   = reinterpret_cast<unsigned*>(ws + WS_HIST);
    unsigned* curs   = reinterpret_cast<unsigned*>(ws + WS_CURS);
    unsigned* fbuck  = reinterpret_cast<unsigned*>(ws + WS_FBUCK); // flist then bucket
    float*    ws_acc = ws + WS_ACC;
    float*    dpart  = ws + WS_DPART;
    unsigned* nflag  = reinterpret_cast<unsigned*>(ws + WS_NFLAG);
    vq_prep<<<256, 256, 0, stream>>>(embed, ws, out, 2);
    vq_distm<<<NROWS / 128, 256, 0, stream>>>(input, ws, jidx, nflag, fbuck);
    vq_refine<<<512, 256, 0, stream>>>(input, embed, ws, nflag, fbuck, jidx);
    vq_hist<<<128, 256, 0, stream>>>(jidx, hist);
    vq_scan<<<1, 512, 0, stream>>>(hist, curs, out);
    vq_scatter<<<NROWS / 256, 256, 0, stream>>>(jidx, curs, fbuck);
    vq_finsum2<<<NWAVE_FIN / 4, 256, 0, stream>>>(input, ws, jidx, fbuck,
                                                  ws_acc, dpart, out);
    vq_es<<<NEMB * DIM / 256, 256, 0, stream>>>(ws_acc, dpart, out, NWAVE_FIN);
  } else {
    vq_prep<<<256, 256, 0, stream>>>(embed, ws, out, 0);
    vq_mono<<<NROWS / 256, 256, 0, stream>>>(input, embed, ws, out);
  }
}